// Round 4
// baseline (1106.737 us; speedup 1.0000x reference)
//
#include <hip/hip_runtime.h>

#define HWX 4096   // 64*64 pixels per (b, channel) plane

typedef __bf16 bf8 __attribute__((ext_vector_type(8)));
typedef __bf16 bf4v __attribute__((ext_vector_type(4)));
typedef float f4 __attribute__((ext_vector_type(4)));

// ---------------- weight pack: fp32 [Cout][Cin][taps] -> bf16 hi/lo [CoutPad][taps][Cin] ----------------
__global__ __launch_bounds__(256) void packw_k(
    const float* __restrict__ w, __bf16* __restrict__ whi, __bf16* __restrict__ wlo,
    int Cout, int CoutPad, int Cin, int taps)
{
  const int idx = blockIdx.x * 256 + threadIdx.x;
  const int tot = CoutPad * taps * Cin;
  if (idx >= tot) return;
  const int co = idx / (taps * Cin);
  const int rem = idx - co * taps * Cin;
  const int tap = rem / Cin;
  const int ci = rem - tap * Cin;
  const float v = (co < Cout) ? w[((size_t)co * Cin + ci) * taps + tap] : 0.f;
  const __bf16 h = (__bf16)v;
  whi[idx] = h;
  wlo[idx] = (__bf16)(v - (float)h);
}

// ---------------- zero the x-halo border columns of an NHWC padded hi/lo buffer ----------------
// rows = 8*64 = 512 (b*64+y); 2 sides; C channels. Cl2 = log2(C).
__global__ __launch_bounds__(256) void zerob_k(
    __bf16* __restrict__ h, __bf16* __restrict__ l, int Cl2)
{
  const int idx = blockIdx.x * 256 + threadIdx.x;
  const int C = 1 << Cl2;
  if (idx >= (512 * 2) << Cl2) return;
  const int c = idx & (C - 1);
  const int r2 = idx >> Cl2;
  const int row = r2 >> 1, side = r2 & 1;
  const size_t a = ((size_t)row * 66 + (side ? 65 : 0)) * C + c;
  h[a] = (__bf16)0.f;
  l[a] = (__bf16)0.f;
}

// ---------------- pack f/fh (fp32 NCHW) -> c1 concat buffer (bf16 hi/lo, NHWC, x-padded 66) ----------------
// grid (64 y, 8 b, 2 src). LDS transpose: [256 ch][65] u32 (hi<<16|lo).
__global__ __launch_bounds__(256) void packin_k(
    const float* __restrict__ f, const float* __restrict__ fh,
    __bf16* __restrict__ c1h, __bf16* __restrict__ c1l)
{
  __shared__ unsigned tile[256][65];
  const int y = blockIdx.x, b = blockIdx.y, z = blockIdx.z;
  const float* __restrict__ src = (z == 0) ? f : fh;
  const int t = threadIdx.x;
  const int xl = t & 63, cq = t >> 6;
  for (int i = 0; i < 64; ++i) {
    const int ch = cq * 64 + i;
    const float v = src[(((size_t)b * 256 + ch) << 12) + (y << 6) + xl];
    const __bf16 h = (__bf16)v;
    const __bf16 lo = (__bf16)(v - (float)h);
    tile[ch][xl] = ((unsigned)__builtin_bit_cast(unsigned short, h) << 16)
                 | (unsigned)__builtin_bit_cast(unsigned short, lo);
  }
  __syncthreads();
  const int xr = t & 63, chunk = t >> 6;   // 64 ch per thread
  const size_t base = ((size_t)(b * 64 + y) * 66 + xr + 1) * 512 + z * 256 + chunk * 64;
  for (int i8 = 0; i8 < 8; ++i8) {
    bf8 hv, lv;
#pragma unroll
    for (int j = 0; j < 8; ++j) {
      const unsigned u = tile[chunk * 64 + i8 * 8 + j][xr];
      hv[j] = __builtin_bit_cast(__bf16, (unsigned short)(u >> 16));
      lv[j] = __builtin_bit_cast(__bf16, (unsigned short)(u & 0xffffu));
    }
    *reinterpret_cast<bf8*>(c1h + base + i8 * 8) = hv;
    *reinterpret_cast<bf8*>(c1l + base + i8 * 8) = lv;
  }
}

// ---------------- MFMA implicit-GEMM conv v2: NHWC bf16 hi/lo input, padded x ----------------
// OUTM 0: fp32 NCHW out.  OUTM 1: bf16 hi/lo NHWC padded out (interior only).
template<int NCOW, int TAPS, int OUTM, bool RELU>
__global__ __launch_bounds__(256) void convmm2_k(
    const __bf16* __restrict__ inH, const __bf16* __restrict__ inL,
    const __bf16* __restrict__ whi, const __bf16* __restrict__ wlo,
    const float* __restrict__ bias,
    float* __restrict__ outF, __bf16* __restrict__ outH, __bf16* __restrict__ outL,
    int Cin, int Cout, int CoutBuf)
{
  const int lane = threadIdx.x & 63;
  const int wv = threadIdx.x >> 6;
  const int wco = wv % NCOW;
  const int yg = wv / NCOW;
  constexpr int ROWS = 4 / NCOW;
  const int pb = blockIdx.x * ROWS + yg;         // global image row 0..511
  const int b = pb >> 6, y = pb & 63;
  const int co0 = blockIdx.y * (16 * NCOW) + wco * 16;
  const int colb = lane & 15;
  const int g = lane >> 4;

  f4 acc[4] = {f4{0,0,0,0}, f4{0,0,0,0}, f4{0,0,0,0}, f4{0,0,0,0}};
  const size_t wbase = (size_t)(co0 + colb) * TAPS * Cin;
  const size_t rowpitch = (size_t)66 * Cin;

  for (int tap = 0; tap < TAPS; ++tap) {
    int dxm1 = 0, gy = y;
    if (TAPS == 9) {
      const int dy = tap / 3;
      dxm1 = tap - dy * 3 - 1;
      gy = y + dy - 1;
      if ((unsigned)gy >= 64u) continue;         // wave-uniform: zero-pad row
    }
    const size_t inrow = (size_t)(b * 64 + gy) * rowpitch + Cin;   // x=0 position
    for (int ci0 = 0; ci0 < Cin; ci0 += 32) {
      const size_t wo = wbase + (size_t)tap * Cin + ci0 + g * 8;
      const bf8 ah = *reinterpret_cast<const bf8*>(whi + wo);
      const bf8 al = *reinterpret_cast<const bf8*>(wlo + wo);
      const size_t ib = inrow + ci0 + g * 8;
#pragma unroll
      for (int fr = 0; fr < 4; ++fr) {
        const int xe = fr * 16 + colb + dxm1;    // -1..64, always in padded range
        const size_t off = ib + (size_t)xe * Cin;
        const bf8 bh = *reinterpret_cast<const bf8*>(inH + off);
        const bf8 bl = *reinterpret_cast<const bf8*>(inL + off);
        acc[fr] = __builtin_amdgcn_mfma_f32_16x16x32_bf16(ah, bh, acc[fr], 0, 0, 0);
        acc[fr] = __builtin_amdgcn_mfma_f32_16x16x32_bf16(ah, bl, acc[fr], 0, 0, 0);
        acc[fr] = __builtin_amdgcn_mfma_f32_16x16x32_bf16(al, bh, acc[fr], 0, 0, 0);
      }
    }
  }

  if (OUTM == 0) {
    const size_t ob = ((size_t)b * Cout) << 12;
#pragma unroll
    for (int r = 0; r < 4; ++r) {
      const int co = co0 + g * 4 + r;
      if (co < Cout) {
        const float bv = bias[co];
#pragma unroll
        for (int fr = 0; fr < 4; ++fr) {
          float v = acc[fr][r] + bv;
          if (RELU) v = fmaxf(v, 0.f);
          outF[ob + ((size_t)co << 12) + (y << 6) + fr * 16 + colb] = v;
        }
      }
    }
  } else {
    float bv[4];
#pragma unroll
    for (int r = 0; r < 4; ++r) bv[r] = bias[co0 + g * 4 + r];
#pragma unroll
    for (int fr = 0; fr < 4; ++fr) {
      bf4v hv, lv;
#pragma unroll
      for (int r = 0; r < 4; ++r) {
        float v = acc[fr][r] + bv[r];
        if (RELU) v = fmaxf(v, 0.f);
        const __bf16 h = (__bf16)v;
        hv[r] = h;
        lv[r] = (__bf16)(v - (float)h);
      }
      const int px = fr * 16 + colb;
      const size_t oadr = ((size_t)(b * 64 + y) * 66 + px + 1) * CoutBuf + co0 + g * 4;
      *reinterpret_cast<bf4v*>(outH + oadr) = hv;
      *reinterpret_cast<bf4v*>(outL + oadr) = lv;
    }
  }
}

// ---------------- assemble v2: fp32 compute; writes alg fp32 NCHW + aligned-half of c1 (NHWC hi/lo) ----------------
__global__ __launch_bounds__(256) void assemble2_k(
    const float* __restrict__ atten, const float* __restrict__ fh,
    float* __restrict__ alg, __bf16* __restrict__ c1h, __bf16* __restrict__ c1l)
{
  __shared__ unsigned smem[128 * 65];            // 33.3 KB; first 5184 u32 alias att[81][64]
  float* att = reinterpret_cast<float*>(smem);
  const int b = blockIdx.y, y = blockIdx.x;
  for (int e = threadIdx.x; e < 81 * 64; e += 256) {
    const int i = e >> 6, x = e & 63;
    att[i * 64 + x] = atten[(((size_t)b * 81 + i) << 12) + (y << 6) + x];
  }
  __syncthreads();

  const int quad = threadIdx.x & 15, x0 = quad << 2;
  const int csub = threadIdx.x >> 4;

  float acc[16][4];
#pragma unroll
  for (int i = 0; i < 16; ++i) {
    acc[i][0] = 0.f; acc[i][1] = 0.f; acc[i][2] = 0.f; acc[i][3] = 0.f;
  }

#pragma unroll
  for (int dy = 0; dy < 9; ++dy) {
    const int gy = y + dy - 4;
    if (gy < 0 || gy >= 64) continue;
    float av[9][4];
#pragma unroll
    for (int dx = 0; dx < 9; ++dx) {
      const float4 q = *reinterpret_cast<const float4*>(&att[(dy * 9 + dx) * 64 + x0]);
      av[dx][0] = q.x; av[dx][1] = q.y; av[dx][2] = q.z; av[dx][3] = q.w;
    }
#pragma unroll
    for (int cb = 0; cb < 16; ++cb) {
      const int ch = cb * 16 + csub;
      const float* row = fh + (((size_t)b * 256 + ch) << 12) + (gy << 6);
      float rv[12];
#pragma unroll
      for (int k = 0; k < 3; ++k) {
        const int col0 = x0 - 4 + (k << 2);
        if (col0 >= 0 && col0 + 3 < 64) {
          const float4 q = *reinterpret_cast<const float4*>(row + col0);
          rv[4 * k + 0] = q.x; rv[4 * k + 1] = q.y; rv[4 * k + 2] = q.z; rv[4 * k + 3] = q.w;
        } else {
#pragma unroll
          for (int jj = 0; jj < 4; ++jj) {
            const int cl = col0 + jj;
            rv[4 * k + jj] = (cl >= 0 && cl < 64) ? row[cl] : 0.f;
          }
        }
      }
#pragma unroll
      for (int dx = 0; dx < 9; ++dx)
#pragma unroll
        for (int j = 0; j < 4; ++j)
          acc[cb][j] = fmaf(av[dx][j], rv[dx + j], acc[cb][j]);
    }
  }

  // alg fp32 NCHW (coalesced float4)
#pragma unroll
  for (int cb = 0; cb < 16; ++cb) {
    const int ch = cb * 16 + csub;
    float4 q;
    q.x = acc[cb][0]; q.y = acc[cb][1]; q.z = acc[cb][2]; q.w = acc[cb][3];
    *reinterpret_cast<float4*>(alg + (((size_t)b * 256 + ch) << 12) + (y << 6) + x0) = q;
  }

  // NHWC hi/lo into c1 channels 256..511, two 128-channel passes through LDS
  const size_t rowbase = (size_t)(b * 64 + y) * 66;
  const int xr = threadIdx.x & 63, cpart = threadIdx.x >> 6;   // 32 ch per thread per pass
  for (int p = 0; p < 2; ++p) {
    __syncthreads();   // previous readers (att / prior pass) done
#pragma unroll
    for (int cb = p * 8; cb < p * 8 + 8; ++cb) {
      const int chl = (cb - p * 8) * 16 + csub;
#pragma unroll
      for (int j = 0; j < 4; ++j) {
        const float v = acc[cb][j];
        const __bf16 h = (__bf16)v;
        const __bf16 lo = (__bf16)(v - (float)h);
        smem[chl * 65 + x0 + j] = ((unsigned)__builtin_bit_cast(unsigned short, h) << 16)
                                | (unsigned)__builtin_bit_cast(unsigned short, lo);
      }
    }
    __syncthreads();
    const size_t obase = (rowbase + xr + 1) * 512 + 256 + p * 128 + cpart * 32;
    for (int i8 = 0; i8 < 4; ++i8) {
      bf8 hv, lv;
#pragma unroll
      for (int j = 0; j < 8; ++j) {
        const unsigned u = smem[(cpart * 32 + i8 * 8 + j) * 65 + xr];
        hv[j] = __builtin_bit_cast(__bf16, (unsigned short)(u >> 16));
        lv[j] = __builtin_bit_cast(__bf16, (unsigned short)(u & 0xffffu));
      }
      *reinterpret_cast<bf8*>(c1h + obase + i8 * 8) = hv;
      *reinterpret_cast<bf8*>(c1l + obase + i8 * 8) = lv;
    }
  }
}

// ================= round-3 fallback kernels (used if ws too small) =================
template<int NCOW, int TAPS, bool RELU, bool CONCAT>
__global__ __launch_bounds__(256) void convmm_k(
    const float* __restrict__ inA, const float* __restrict__ inB,
    const __bf16* __restrict__ whi, const __bf16* __restrict__ wlo,
    const float* __restrict__ bias,
    float* __restrict__ out, int CinA, int CinTot, int Cout)
{
  const int lane = threadIdx.x & 63;
  const int wv = threadIdx.x >> 6;
  const int wco = wv % NCOW;
  const int yg = wv / NCOW;
  constexpr int ROWS = 4 / NCOW;
  const int pb = blockIdx.x * ROWS + yg;
  const int b = pb >> 6, y = pb & 63;
  const int co0 = blockIdx.y * (16 * NCOW) + wco * 16;
  const int colb = lane & 15;
  const int g = lane >> 4;

  f4 acc[4] = {f4{0,0,0,0}, f4{0,0,0,0}, f4{0,0,0,0}, f4{0,0,0,0}};
  const size_t wbase = (size_t)(co0 + colb) * TAPS * CinTot;

  for (int tap = 0; tap < TAPS; ++tap) {
    int dxm1 = 0, gy = y;
    if (TAPS == 9) {
      const int dy = tap / 3;
      dxm1 = tap - dy * 3 - 1;
      gy = y + dy - 1;
      if ((unsigned)gy >= 64u) continue;
    }
    const int rowoff = gy << 6;
    for (int ci0 = 0; ci0 < CinTot; ci0 += 32) {
      const size_t wo = wbase + (size_t)tap * CinTot + ci0 + g * 8;
      const bf8 ah = *reinterpret_cast<const bf8*>(whi + wo);
      const bf8 al = *reinterpret_cast<const bf8*>(wlo + wo);
      const int cibase = ci0 + g * 8;
      const float* src;
      if (CONCAT) {
        src = (cibase < CinA) ? inA + (((size_t)b * CinA + cibase) << 12)
                              : inB + (((size_t)b * CinA + (cibase - CinA)) << 12);
      } else {
        src = inA + (((size_t)b * CinTot + cibase) << 12);
      }
      src += rowoff;
#pragma unroll
      for (int fr = 0; fr < 4; ++fr) {
        const int xe = fr * 16 + colb + dxm1;
        const bool ok = (TAPS == 1) || ((unsigned)xe < 64u);
        const float* sp = src + xe;
        bf8 bh, bl;
#pragma unroll
        for (int j = 0; j < 8; ++j) {
          const float v = ok ? sp[(size_t)j << 12] : 0.f;
          const __bf16 h = (__bf16)v;
          bh[j] = h;
          bl[j] = (__bf16)(v - (float)h);
        }
        acc[fr] = __builtin_amdgcn_mfma_f32_16x16x32_bf16(ah, bh, acc[fr], 0, 0, 0);
        acc[fr] = __builtin_amdgcn_mfma_f32_16x16x32_bf16(ah, bl, acc[fr], 0, 0, 0);
        acc[fr] = __builtin_amdgcn_mfma_f32_16x16x32_bf16(al, bh, acc[fr], 0, 0, 0);
      }
    }
  }

  const size_t ob = ((size_t)b * Cout) << 12;
#pragma unroll
  for (int r = 0; r < 4; ++r) {
    const int co = co0 + g * 4 + r;
    if (co < Cout) {
      const float bv = bias[co];
#pragma unroll
      for (int fr = 0; fr < 4; ++fr) {
        float v = acc[fr][r] + bv;
        if (RELU) v = fmaxf(v, 0.f);
        out[ob + ((size_t)co << 12) + (y << 6) + fr * 16 + colb] = v;
      }
    }
  }
}

__global__ __launch_bounds__(256) void assemble_k(
    const float* __restrict__ atten, const float* __restrict__ fh,
    float* __restrict__ out)
{
  __shared__ float att[81][64];
  const int b = blockIdx.y, y = blockIdx.x;
  for (int e = threadIdx.x; e < 81 * 64; e += 256) {
    const int i = e >> 6, x = e & 63;
    att[i][x] = atten[(((size_t)b * 81 + i) << 12) + (y << 6) + x];
  }
  __syncthreads();

  const int quad = threadIdx.x & 15, x0 = quad << 2;
  const int csub = threadIdx.x >> 4;

  float acc[16][4];
#pragma unroll
  for (int i = 0; i < 16; ++i) {
    acc[i][0] = 0.f; acc[i][1] = 0.f; acc[i][2] = 0.f; acc[i][3] = 0.f;
  }

#pragma unroll
  for (int dy = 0; dy < 9; ++dy) {
    const int gy = y + dy - 4;
    if (gy < 0 || gy >= 64) continue;
    float av[9][4];
#pragma unroll
    for (int dx = 0; dx < 9; ++dx) {
      const float4 q = *reinterpret_cast<const float4*>(&att[dy * 9 + dx][x0]);
      av[dx][0] = q.x; av[dx][1] = q.y; av[dx][2] = q.z; av[dx][3] = q.w;
    }
#pragma unroll
    for (int cb = 0; cb < 16; ++cb) {
      const int ch = cb * 16 + csub;
      const float* row = fh + (((size_t)b * 256 + ch) << 12) + (gy << 6);
      float rv[12];
#pragma unroll
      for (int k = 0; k < 3; ++k) {
        const int col0 = x0 - 4 + (k << 2);
        if (col0 >= 0 && col0 + 3 < 64) {
          const float4 q = *reinterpret_cast<const float4*>(row + col0);
          rv[4 * k + 0] = q.x; rv[4 * k + 1] = q.y; rv[4 * k + 2] = q.z; rv[4 * k + 3] = q.w;
        } else {
#pragma unroll
          for (int jj = 0; jj < 4; ++jj) {
            const int cl = col0 + jj;
            rv[4 * k + jj] = (cl >= 0 && cl < 64) ? row[cl] : 0.f;
          }
        }
      }
#pragma unroll
      for (int dx = 0; dx < 9; ++dx)
#pragma unroll
        for (int j = 0; j < 4; ++j)
          acc[cb][j] = fmaf(av[dx][j], rv[dx + j], acc[cb][j]);
    }
  }

#pragma unroll
  for (int cb = 0; cb < 16; ++cb) {
    const int ch = cb * 16 + csub;
    float4 q;
    q.x = acc[cb][0]; q.y = acc[cb][1]; q.z = acc[cb][2]; q.w = acc[cb][3];
    *reinterpret_cast<float4*>(out + (((size_t)b * 256 + ch) << 12) + (y << 6) + x0) = q;
  }
}

// ---------------- shared tail kernels ----------------
template<int TCO, bool RELU>
__global__ __launch_bounds__(256) void conv3x3_k(
    const float* __restrict__ in, const float* __restrict__ w,
    const float* __restrict__ bias, float* __restrict__ out,
    int Cin, int Cout)
{
  __shared__ float tile[8][6][66];
  const int b = blockIdx.z;
  const int y0 = blockIdx.x * 4;
  const int co0 = blockIdx.y * TCO;
  const int r = threadIdx.x >> 6;
  const int c = threadIdx.x & 63;

  float acc[TCO];
#pragma unroll
  for (int i = 0; i < TCO; ++i) acc[i] = 0.f;

  for (int ci0 = 0; ci0 < Cin; ci0 += 8) {
    __syncthreads();
    for (int e = threadIdx.x; e < 8 * 6 * 66; e += 256) {
      const int cc = e / 396;
      const int rem = e - cc * 396;
      const int rr = rem / 66;
      const int xx = rem - rr * 66;
      const int gy = y0 + rr - 1;
      const int gx = xx - 1;
      float v = 0.f;
      if (gy >= 0 && gy < 64 && gx >= 0 && gx < 64)
        v = in[(((size_t)b * Cin + ci0 + cc) << 12) + (gy << 6) + gx];
      tile[cc][rr][xx] = v;
    }
    __syncthreads();
    for (int cc = 0; cc < 8; ++cc) {
      const float x00 = tile[cc][r + 0][c + 0], x01 = tile[cc][r + 0][c + 1], x02 = tile[cc][r + 0][c + 2];
      const float x10 = tile[cc][r + 1][c + 0], x11 = tile[cc][r + 1][c + 1], x12 = tile[cc][r + 1][c + 2];
      const float x20 = tile[cc][r + 2][c + 0], x21 = tile[cc][r + 2][c + 1], x22 = tile[cc][r + 2][c + 2];
#pragma unroll
      for (int co = 0; co < TCO; ++co) {
        const float* wp = w + ((size_t)(co0 + co) * Cin + (ci0 + cc)) * 9;
        float s = acc[co];
        s = fmaf(x00, wp[0], s); s = fmaf(x01, wp[1], s); s = fmaf(x02, wp[2], s);
        s = fmaf(x10, wp[3], s); s = fmaf(x11, wp[4], s); s = fmaf(x12, wp[5], s);
        s = fmaf(x20, wp[6], s); s = fmaf(x21, wp[7], s); s = fmaf(x22, wp[8], s);
        acc[co] = s;
      }
    }
  }

#pragma unroll
  for (int co = 0; co < TCO; ++co) {
    if (co0 + co < Cout) {
      float v = acc[co] + bias[co0 + co];
      if (RELU) v = fmaxf(v, 0.f);
      out[(((size_t)b * Cout + (co0 + co)) << 12) + ((y0 + r) << 6) + c] = v;
    }
  }
}

__global__ __launch_bounds__(256) void logits_softmax_k(
    const float* __restrict__ g3, const float* __restrict__ fw4,
    const float* __restrict__ fb4, float* __restrict__ score)
{
  const int pix = blockIdx.x * 256 + threadIdx.x;
  const int b = pix >> 12, pp = pix & 4095;
  const int y = pp >> 6, x = pp & 63;
  float l0 = fb4[0], l1 = fb4[1];
#pragma unroll
  for (int ci = 0; ci < 3; ++ci) {
    const float* g = g3 + (((size_t)b * 3 + ci) << 12);
#pragma unroll
    for (int dy = 0; dy < 3; ++dy) {
      const int gy = y + dy - 1;
      if (gy < 0 || gy >= 64) continue;
#pragma unroll
      for (int dx = 0; dx < 3; ++dx) {
        const int gx = x + dx - 1;
        if (gx < 0 || gx >= 64) continue;
        const float v = g[(gy << 6) + gx];
        l0 = fmaf(v, fw4[(0 * 3 + ci) * 9 + dy * 3 + dx], l0);
        l1 = fmaf(v, fw4[(1 * 3 + ci) * 9 + dy * 3 + dx], l1);
      }
    }
  }
  const float m = fmaxf(l0, l1);
  const float e0 = __expf(l0 - m), e1 = __expf(l1 - m);
  const float inv = 1.f / (e0 + e1);
  score[((size_t)b * 2 + 0) * HWX + pp] = e0 * inv;
  score[((size_t)b * 2 + 1) * HWX + pp] = e1 * inv;
}

__global__ __launch_bounds__(256) void blend_k(
    const float* __restrict__ score, const float* __restrict__ f,
    const float* __restrict__ alg, float* __restrict__ out)
{
  const size_t q = (size_t)blockIdx.x * 256 + threadIdx.x;
  const size_t e = q << 2;
  const int b = (int)(e >> 20);
  const int rem = (int)(e & 1048575);
  const int pp = rem & 4095;
  const float4 s0 = *reinterpret_cast<const float4*>(score + ((size_t)b * 2 + 0) * HWX + pp);
  const float4 s1 = *reinterpret_cast<const float4*>(score + ((size_t)b * 2 + 1) * HWX + pp);
  const float4 fv = *reinterpret_cast<const float4*>(f + e);
  const float4 av = *reinterpret_cast<const float4*>(alg + e);
  float4 o;
  o.x = s0.x * fv.x + s1.x * av.x;
  o.y = s0.y * fv.y + s1.y * av.y;
  o.z = s0.z * fv.z + s1.z * av.z;
  o.w = s0.w * fv.w + s1.w * av.w;
  *reinterpret_cast<float4*>(out + e) = o;
}

extern "C" void kernel_launch(void* const* d_in, const int* in_sizes, int n_in,
                              void* d_out, int out_size, void* d_ws, size_t ws_size,
                              hipStream_t stream) {
  const float* f   = (const float*)d_in[0];
  const float* fh  = (const float*)d_in[1];
  const float* aw1 = (const float*)d_in[2];
  const float* ab1 = (const float*)d_in[3];
  const float* aw2 = (const float*)d_in[4];
  const float* ab2 = (const float*)d_in[5];
  const float* aw3 = (const float*)d_in[6];
  const float* ab3 = (const float*)d_in[7];
  const float* fw1 = (const float*)d_in[8];
  const float* fb1 = (const float*)d_in[9];
  const float* fw2 = (const float*)d_in[10];
  const float* fb2 = (const float*)d_in[11];
  const float* fw3 = (const float*)d_in[12];
  const float* fb3 = (const float*)d_in[13];
  const float* fw4 = (const float*)d_in[14];
  const float* fb4 = (const float*)d_in[15];
  float* out = (float*)d_out;

  dim3 blk(256);
  const size_t NEED = 171000000;   // bytes for the NHWC fast path

  if (ws_size >= NEED) {
    // ---------- fast path layout ----------
    char* p = (char*)d_ws;
    float*  att    = (float*)p;              p += (size_t)2654208 * 4;
    float*  alg    = (float*)p;              p += (size_t)8388608 * 4;
    float*  g2     = (float*)p;              p += (size_t)524288 * 4;
    float*  g3b    = (float*)p;              p += (size_t)98304 * 4;
    float*  scoreb = (float*)p;              p += (size_t)65536 * 4;
    __bf16* c1h    = (__bf16*)p;             p += (size_t)17301504 * 2;
    __bf16* c1l    = (__bf16*)p;             p += (size_t)17301504 * 2;
    __bf16* a1h    = (__bf16*)p;             p += (size_t)8650752 * 2;
    __bf16* a1l    = (__bf16*)p;             p += (size_t)8650752 * 2;
    __bf16* a2h    = (__bf16*)p;             p += (size_t)4325376 * 2;
    __bf16* a2l    = (__bf16*)p;             p += (size_t)4325376 * 2;
    __bf16* w1h    = (__bf16*)p;             p += (size_t)131072 * 2;
    __bf16* w1l    = (__bf16*)p;             p += (size_t)131072 * 2;
    __bf16* w2h    = (__bf16*)p;             p += (size_t)294912 * 2;
    __bf16* w2l    = (__bf16*)p;             p += (size_t)294912 * 2;
    __bf16* w3h    = (__bf16*)p;             p += (size_t)110592 * 2;
    __bf16* w3l    = (__bf16*)p;             p += (size_t)110592 * 2;
    __bf16* f1h    = (__bf16*)p;             p += (size_t)131072 * 2;
    __bf16* f1l    = (__bf16*)p;             p += (size_t)131072 * 2;
    __bf16* f2h    = (__bf16*)p;             p += (size_t)36864 * 2;
    __bf16* f2l    = (__bf16*)p;             p += (size_t)36864 * 2;

    packw_k<<<dim3(512),  blk, 0, stream>>>(aw1, w1h, w1l, 256, 256, 512, 1);
    packw_k<<<dim3(1152), blk, 0, stream>>>(aw2, w2h, w2l, 128, 128, 256, 9);
    packw_k<<<dim3(432),  blk, 0, stream>>>(aw3, w3h, w3l, 81, 96, 128, 9);
    packw_k<<<dim3(512),  blk, 0, stream>>>(fw1, f1h, f1l, 256, 256, 512, 1);
    packw_k<<<dim3(144),  blk, 0, stream>>>(fw2, f2h, f2l, 16, 16, 256, 9);
    zerob_k<<<dim3(1024), blk, 0, stream>>>(a1h, a1l, 8);
    zerob_k<<<dim3(512),  blk, 0, stream>>>(a2h, a2l, 7);
    packin_k<<<dim3(64, 8, 2), blk, 0, stream>>>(f, fh, c1h, c1l);

    // atten path
    convmm2_k<4, 1, 1, true ><<<dim3(512, 4), blk, 0, stream>>>(c1h, c1l, w1h, w1l, ab1, nullptr, a1h, a1l, 512, 256, 256);
    convmm2_k<4, 9, 1, true ><<<dim3(512, 2), blk, 0, stream>>>(a1h, a1l, w2h, w2l, ab2, nullptr, a2h, a2l, 256, 128, 128);
    convmm2_k<2, 9, 0, false><<<dim3(256, 3), blk, 0, stream>>>(a2h, a2l, w3h, w3l, ab3, att, nullptr, nullptr, 128, 81, 0);
    // assemble: alg fp32 + aligned-half of c1 (ch 256..511)
    assemble2_k<<<dim3(64, 8), blk, 0, stream>>>(att, fh, alg, c1h, c1l);
    // final path (c1 now holds [f | aligned])
    convmm2_k<4, 1, 1, true ><<<dim3(512, 4), blk, 0, stream>>>(c1h, c1l, f1h, f1l, fb1, nullptr, a1h, a1l, 512, 256, 256);
    convmm2_k<1, 9, 0, true ><<<dim3(128, 1), blk, 0, stream>>>(a1h, a1l, f2h, f2l, fb2, g2, nullptr, nullptr, 256, 16, 0);
    conv3x3_k<3, false><<<dim3(16, 1, 8), blk, 0, stream>>>(g2, fw3, fb3, g3b, 16, 3);
    logits_softmax_k<<<dim3(128), blk, 0, stream>>>(g3b, fw4, fb4, scoreb);
    blend_k<<<dim3(8192), blk, 0, stream>>>(scoreb, f, alg, out);
  } else {
    // ---------- round-3 fallback ----------
    float* ws = (float*)d_ws;
    float* a1     = ws;
    float* a2     = a1 + 8388608;
    float* att    = a2 + 4194304;
    float* alg    = att + 2654208;
    float* g3b    = alg + 8388608;
    float* scoreb = g3b + 98304;
    __bf16* wpkb  = (__bf16*)(scoreb + 65536);
    __bf16* w1h   = wpkb;
    __bf16* w1l   = w1h + 131072;
    __bf16* w2h   = w1l + 131072;
    __bf16* w2l   = w2h + 294912;
    __bf16* w3h   = w2l + 294912;
    __bf16* w3l   = w3h + 110592;
    __bf16* fw1h  = w3l + 110592;
    __bf16* fw1l  = fw1h + 131072;
    __bf16* fw2h  = fw1l + 131072;
    __bf16* fw2l  = fw2h + 36864;

    packw_k<<<dim3(512),  blk, 0, stream>>>(aw1, w1h, w1l, 256, 256, 512, 1);
    packw_k<<<dim3(1152), blk, 0, stream>>>(aw2, w2h, w2l, 128, 128, 256, 9);
    packw_k<<<dim3(432),  blk, 0, stream>>>(aw3, w3h, w3l, 81, 96, 128, 9);
    packw_k<<<dim3(512),  blk, 0, stream>>>(fw1, fw1h, fw1l, 256, 256, 512, 1);
    packw_k<<<dim3(144),  blk, 0, stream>>>(fw2, fw2h, fw2l, 16, 16, 256, 9);

    convmm_k<4, 1, true,  true ><<<dim3(512, 4), blk, 0, stream>>>(f, fh, w1h, w1l, ab1, a1, 256, 512, 256);
    convmm_k<4, 9, true,  false><<<dim3(512, 2), blk, 0, stream>>>(a1, nullptr, w2h, w2l, ab2, a2, 0, 256, 128);
    convmm_k<2, 9, false, false><<<dim3(256, 3), blk, 0, stream>>>(a2, nullptr, w3h, w3l, ab3, att, 0, 128, 81);
    assemble_k<<<dim3(64, 8), blk, 0, stream>>>(att, fh, alg);
    convmm_k<4, 1, true,  true ><<<dim3(512, 4), blk, 0, stream>>>(f, alg, fw1h, fw1l, fb1, a1, 256, 512, 256);
    convmm_k<1, 9, true,  false><<<dim3(128, 1), blk, 0, stream>>>(a1, nullptr, fw2h, fw2l, fb2, a2, 0, 256, 16);
    conv3x3_k<3, false><<<dim3(16, 1, 8), blk, 0, stream>>>(a2, fw3, fb3, g3b, 16, 3);
    logits_softmax_k<<<dim3(128), blk, 0, stream>>>(g3b, fw4, fb4, scoreb);
    blend_k<<<dim3(8192), blk, 0, stream>>>(scoreb, f, alg, out);
  }
}

// Round 5
// 515.387 us; speedup vs baseline: 2.1474x; 2.1474x over previous
//
#include <hip/hip_runtime.h>

typedef __bf16 bf8 __attribute__((ext_vector_type(8)));
typedef float f4 __attribute__((ext_vector_type(4)));
typedef unsigned int u32;
typedef u32 u4v __attribute__((ext_vector_type(4)));

__device__ __forceinline__ u32 packf(float v) {
  const __bf16 h = (__bf16)v;
  const __bf16 l = (__bf16)(v - (float)h);
  return ((u32)__builtin_bit_cast(unsigned short, h) << 16) |
         (u32)__builtin_bit_cast(unsigned short, l);
}
__device__ __forceinline__ float unpackf(u32 u) {
  const float hi = __builtin_bit_cast(float, u & 0xffff0000u);
  const float lo = __builtin_bit_cast(float, u << 16);
  return hi + lo;
}

// ---------------- weight pack: fp32 [Cout][Cin][taps] -> bf16 hi/lo [CoutPad][taps][Cin] ----------------
__global__ __launch_bounds__(256) void packw_k(
    const float* __restrict__ w, __bf16* __restrict__ whi, __bf16* __restrict__ wlo,
    int Cout, int CoutPad, int Cin, int taps)
{
  const int idx = blockIdx.x * 256 + threadIdx.x;
  const int tot = CoutPad * taps * Cin;
  if (idx >= tot) return;
  const int co = idx / (taps * Cin);
  const int rem = idx - co * taps * Cin;
  const int tap = rem / Cin;
  const int ci = rem - tap * Cin;
  const float v = (co < Cout) ? w[((size_t)co * Cin + ci) * taps + tap] : 0.f;
  const __bf16 h = (__bf16)v;
  whi[idx] = h;
  wlo[idx] = (__bf16)(v - (float)h);
}

// ---------------- pack f/fh fp32 NCHW -> C8 packed u32 [b][C/8][4096][8] ----------------
__global__ __launch_bounds__(256) void packin2_k(
    const float* __restrict__ f, const float* __restrict__ fh,
    u32* __restrict__ fpk, u32* __restrict__ fhpk)
{
  const int t = blockIdx.x * 256 + threadIdx.x;   // (b, cgrp, px)
  const int px = t & 4095;
  const int cg = (t >> 12) & 31;
  const int b = t >> 17;
  const float* __restrict__ src = blockIdx.y ? fh : f;
  u32* __restrict__ dst = blockIdx.y ? fhpk : fpk;
  const size_t ib = (((size_t)b * 256 + cg * 8) << 12) + px;
  u4v o0, o1;
#pragma unroll
  for (int j = 0; j < 8; ++j) {
    const u32 p = packf(src[ib + ((size_t)j << 12)]);
    if (j < 4) o0[j] = p; else o1[j - 4] = p;
  }
  const u32 oadr = (u32)b * 1048576u + (u32)cg * 32768u + (u32)px * 8u;
  *reinterpret_cast<u4v*>(dst + oadr) = o0;
  *reinterpret_cast<u4v*>(dst + oadr + 4) = o1;
}

// ---------------- MFMA implicit-GEMM conv, C8-packed inputs ----------------
// Block 256 thr = 4 waves. WCO waves along couts (wave = COT tiles of 16 couts), 4/WCO rows.
// TAPS==9 inputs are padded planes [66][66]; TAPS==1 inputs unpadded [64][64].
// OUTM 0: fp32 NCHW out (COUTB planes). OUTM 1: packed padded C8 out (COUTB channels).
template<int CIN, int COT, int WCO, int TAPS, int OUTM, int COUTB, bool RELU, bool CONCAT>
__global__ __launch_bounds__(256, 2) void convp_k(
    const u32* __restrict__ inA, const u32* __restrict__ inB,
    const __bf16* __restrict__ whi, const __bf16* __restrict__ wlo,
    const float* __restrict__ bias,
    float* __restrict__ outF, u32* __restrict__ outP, int Cout)
{
  constexpr int RPB = 4 / WCO;
  constexpr int KQ = CIN / 32;
  constexpr int NS = TAPS * KQ;                       // all even
  constexpr u32 PL8IN = (TAPS == 9) ? 34848u : 32768u;
  constexpr u32 BSTR = CONCAT ? 1048576u : (u32)(CIN / 8) * PL8IN;
  constexpr u32 OBSTR = (u32)(COUTB / 8) * 34848u;

  const int lane = threadIdx.x & 63;
  const int wv = threadIdx.x >> 6;
  const int wco = (WCO == 4) ? wv : 0;
  const int rg = (WCO == 4) ? 0 : wv;
  const int pb = blockIdx.x * RPB + rg;
  const int b = pb >> 6, y = pb & 63;
  const int co0 = blockIdx.y * (16 * COT * WCO) + wco * (16 * COT);
  if (co0 >= Cout) return;                            // wave-uniform; no barriers in kernel
  const int colb = lane & 15, g = lane >> 4;

  f4 acc[COT][4];
#pragma unroll
  for (int t = 0; t < COT; ++t)
#pragma unroll
    for (int fr = 0; fr < 4; ++fr) acc[t][fr] = f4{0.f, 0.f, 0.f, 0.f};

  auto LOAD = [&](int s, u4v (&B)[4][2], bf8 (&AH)[COT], bf8 (&AL)[COT]) {
    int tap, kq;
    if (TAPS == 9) { kq = (s * 57) >> 9; tap = s - kq * 9; }   // s = kq*9+tap
    else { kq = s; tap = 0; }
    const int cib = (kq << 5) + g * 8;
    int rc;
    if (TAPS == 9) {
      const int dy = (tap * 11) >> 5;                 // tap/3
      const int dxm1 = tap - dy * 3 - 1;
      const int gy = y + dy - 1;                      // -1..64, padded
      rc = (gy + 1) * 66 + colb + dxm1 + 1;
    } else {
      rc = (y << 6) + colb;
    }
    const u32* src = inA;
    int cg = cib >> 3;
    if (CONCAT) { if (cib >= 256) src = inB; cg = (cib & 255) >> 3; }
    const u32 off = (u32)b * BSTR + (u32)cg * PL8IN + (u32)rc * 8u;
#pragma unroll
    for (int fr = 0; fr < 4; ++fr) {
      B[fr][0] = *reinterpret_cast<const u4v*>(src + off + fr * 128u);
      B[fr][1] = *reinterpret_cast<const u4v*>(src + off + fr * 128u + 4u);
    }
#pragma unroll
    for (int t = 0; t < COT; ++t) {
      const size_t wo = (size_t)(co0 + t * 16 + colb) * (TAPS * CIN) + tap * CIN + cib;
      AH[t] = *reinterpret_cast<const bf8*>(whi + wo);
      AL[t] = *reinterpret_cast<const bf8*>(wlo + wo);
    }
  };

  auto COMPUTE = [&](u4v (&B)[4][2], bf8 (&AH)[COT], bf8 (&AL)[COT]) {
#pragma unroll
    for (int fr = 0; fr < 4; ++fr) {
      u4v hw, lw;
#pragma unroll
      for (int d = 0; d < 4; ++d) {
        const u32 E = (d < 2) ? B[fr][0][2 * d]     : B[fr][1][2 * d - 4];
        const u32 O = (d < 2) ? B[fr][0][2 * d + 1] : B[fr][1][2 * d - 3];
        hw[d] = (E >> 16) | (O & 0xffff0000u);        // foldable to v_perm_b32
        lw[d] = (E & 0xffffu) | (O << 16);
      }
      const bf8 bh = __builtin_bit_cast(bf8, hw);
      const bf8 bl = __builtin_bit_cast(bf8, lw);
#pragma unroll
      for (int t = 0; t < COT; ++t) {
        acc[t][fr] = __builtin_amdgcn_mfma_f32_16x16x32_bf16(AH[t], bh, acc[t][fr], 0, 0, 0);
        acc[t][fr] = __builtin_amdgcn_mfma_f32_16x16x32_bf16(AH[t], bl, acc[t][fr], 0, 0, 0);
        acc[t][fr] = __builtin_amdgcn_mfma_f32_16x16x32_bf16(AL[t], bh, acc[t][fr], 0, 0, 0);
      }
    }
  };

  u4v B0[4][2], B1[4][2];
  bf8 AH0[COT], AL0[COT], AH1[COT], AL1[COT];
  LOAD(0, B0, AH0, AL0);
  for (int s = 0; s < NS; s += 2) {
    LOAD(s + 1, B1, AH1, AL1);        // NS even -> s+1 always valid
    COMPUTE(B0, AH0, AL0);
    if (s + 2 < NS) LOAD(s + 2, B0, AH0, AL0);
    COMPUTE(B1, AH1, AL1);
  }

  if (OUTM == 0) {
    const size_t ob = ((size_t)b * COUTB) << 12;
#pragma unroll
    for (int t = 0; t < COT; ++t)
#pragma unroll
      for (int r = 0; r < 4; ++r) {
        const int co = co0 + t * 16 + g * 4 + r;
        if (co < Cout) {
          const float bv = bias[co];
#pragma unroll
          for (int fr = 0; fr < 4; ++fr) {
            float v = acc[t][fr][r] + bv;
            if (RELU) v = fmaxf(v, 0.f);
            outF[ob + ((size_t)co << 12) + (y << 6) + fr * 16 + colb] = v;
          }
        }
      }
  } else {
#pragma unroll
    for (int t = 0; t < COT; ++t) {
      const int cbase = co0 + t * 16 + g * 4;
      float bv[4];
#pragma unroll
      for (int r = 0; r < 4; ++r) bv[r] = bias[cbase + r];
#pragma unroll
      for (int fr = 0; fr < 4; ++fr) {
        u4v pk;
#pragma unroll
        for (int r = 0; r < 4; ++r) {
          float v = acc[t][fr][r] + bv[r];
          if (RELU) v = fmaxf(v, 0.f);
          pk[r] = packf(v);
        }
        const int px = fr * 16 + colb;
        const u32 oadr = (u32)b * OBSTR + (u32)(cbase >> 3) * 34848u
                       + (u32)((y + 1) * 66 + px + 1) * 8u + (u32)(cbase & 7);
        *reinterpret_cast<u4v*>(outP + oadr) = pk;
      }
    }
  }
}

// ---------------- assemble: fp32 compute; writes aligned as packed C8 unpadded ----------------
__global__ __launch_bounds__(256) void assemble3_k(
    const float* __restrict__ atten, const float* __restrict__ fh,
    u32* __restrict__ algpk)
{
  __shared__ float att[81][64];
  const int b = blockIdx.y, y = blockIdx.x;
  for (int e = threadIdx.x; e < 81 * 64; e += 256) {
    const int i = e >> 6, x = e & 63;
    att[i][x] = atten[(((size_t)b * 81 + i) << 12) + (y << 6) + x];
  }
  __syncthreads();

  const int quad = threadIdx.x & 15, x0 = quad << 2;
  const int csub = threadIdx.x >> 4;

  float acc[16][4];
#pragma unroll
  for (int i = 0; i < 16; ++i) {
    acc[i][0] = 0.f; acc[i][1] = 0.f; acc[i][2] = 0.f; acc[i][3] = 0.f;
  }

#pragma unroll
  for (int dy = 0; dy < 9; ++dy) {
    const int gy = y + dy - 4;
    if (gy < 0 || gy >= 64) continue;
    float av[9][4];
#pragma unroll
    for (int dx = 0; dx < 9; ++dx) {
      const float4 q = *reinterpret_cast<const float4*>(&att[dy * 9 + dx][x0]);
      av[dx][0] = q.x; av[dx][1] = q.y; av[dx][2] = q.z; av[dx][3] = q.w;
    }
#pragma unroll
    for (int cb = 0; cb < 16; ++cb) {
      const int ch = cb * 16 + csub;
      const float* row = fh + (((size_t)b * 256 + ch) << 12) + (gy << 6);
      float rv[12];
#pragma unroll
      for (int k = 0; k < 3; ++k) {
        const int col0 = x0 - 4 + (k << 2);
        if (col0 >= 0 && col0 + 3 < 64) {
          const float4 q = *reinterpret_cast<const float4*>(row + col0);
          rv[4 * k + 0] = q.x; rv[4 * k + 1] = q.y; rv[4 * k + 2] = q.z; rv[4 * k + 3] = q.w;
        } else {
#pragma unroll
          for (int jj = 0; jj < 4; ++jj) {
            const int cl = col0 + jj;
            rv[4 * k + jj] = (cl >= 0 && cl < 64) ? row[cl] : 0.f;
          }
        }
      }
#pragma unroll
      for (int dx = 0; dx < 9; ++dx)
#pragma unroll
        for (int j = 0; j < 4; ++j)
          acc[cb][j] = fmaf(av[dx][j], rv[dx + j], acc[cb][j]);
    }
  }

  const u32 pb2 = (u32)b * 1048576u;
#pragma unroll
  for (int cb = 0; cb < 16; ++cb) {
    const int c = cb * 16 + csub;
    const u32 base = pb2 + (u32)(c >> 3) * 32768u + (u32)(c & 7);
#pragma unroll
    for (int j = 0; j < 4; ++j)
      algpk[base + (u32)((y << 6) + x0 + j) * 8u] = packf(acc[cb][j]);
  }
}

// ---------------- fp32 3x3 conv tail (16->3) ----------------
template<int TCO, bool RELU>
__global__ __launch_bounds__(256) void conv3x3_k(
    const float* __restrict__ in, const float* __restrict__ w,
    const float* __restrict__ bias, float* __restrict__ out,
    int Cin, int Cout)
{
  __shared__ float tile[8][6][66];
  const int b = blockIdx.z;
  const int y0 = blockIdx.x * 4;
  const int co0 = blockIdx.y * TCO;
  const int r = threadIdx.x >> 6;
  const int c = threadIdx.x & 63;

  float acc[TCO];
#pragma unroll
  for (int i = 0; i < TCO; ++i) acc[i] = 0.f;

  for (int ci0 = 0; ci0 < Cin; ci0 += 8) {
    __syncthreads();
    for (int e = threadIdx.x; e < 8 * 6 * 66; e += 256) {
      const int cc = e / 396;
      const int rem = e - cc * 396;
      const int rr = rem / 66;
      const int xx = rem - rr * 66;
      const int gy = y0 + rr - 1;
      const int gx = xx - 1;
      float v = 0.f;
      if (gy >= 0 && gy < 64 && gx >= 0 && gx < 64)
        v = in[(((size_t)b * Cin + ci0 + cc) << 12) + (gy << 6) + gx];
      tile[cc][rr][xx] = v;
    }
    __syncthreads();
    for (int cc = 0; cc < 8; ++cc) {
      const float x00 = tile[cc][r + 0][c + 0], x01 = tile[cc][r + 0][c + 1], x02 = tile[cc][r + 0][c + 2];
      const float x10 = tile[cc][r + 1][c + 0], x11 = tile[cc][r + 1][c + 1], x12 = tile[cc][r + 1][c + 2];
      const float x20 = tile[cc][r + 2][c + 0], x21 = tile[cc][r + 2][c + 1], x22 = tile[cc][r + 2][c + 2];
#pragma unroll
      for (int co = 0; co < TCO; ++co) {
        const float* wp = w + ((size_t)(co0 + co) * Cin + (ci0 + cc)) * 9;
        float s = acc[co];
        s = fmaf(x00, wp[0], s); s = fmaf(x01, wp[1], s); s = fmaf(x02, wp[2], s);
        s = fmaf(x10, wp[3], s); s = fmaf(x11, wp[4], s); s = fmaf(x12, wp[5], s);
        s = fmaf(x20, wp[6], s); s = fmaf(x21, wp[7], s); s = fmaf(x22, wp[8], s);
        acc[co] = s;
      }
    }
  }

#pragma unroll
  for (int co = 0; co < TCO; ++co) {
    if (co0 + co < Cout) {
      float v = acc[co] + bias[co0 + co];
      if (RELU) v = fmaxf(v, 0.f);
      out[(((size_t)b * Cout + (co0 + co)) << 12) + ((y0 + r) << 6) + c] = v;
    }
  }
}

// ---------------- final tiny conv (3->2) + softmax ----------------
__global__ __launch_bounds__(256) void logits_softmax_k(
    const float* __restrict__ g3, const float* __restrict__ fw4,
    const float* __restrict__ fb4, float* __restrict__ score)
{
  const int pix = blockIdx.x * 256 + threadIdx.x;
  const int b = pix >> 12, pp = pix & 4095;
  const int y = pp >> 6, x = pp & 63;
  float l0 = fb4[0], l1 = fb4[1];
#pragma unroll
  for (int ci = 0; ci < 3; ++ci) {
    const float* g = g3 + (((size_t)b * 3 + ci) << 12);
#pragma unroll
    for (int dy = 0; dy < 3; ++dy) {
      const int gy = y + dy - 1;
      if (gy < 0 || gy >= 64) continue;
#pragma unroll
      for (int dx = 0; dx < 3; ++dx) {
        const int gx = x + dx - 1;
        if (gx < 0 || gx >= 64) continue;
        const float v = g[(gy << 6) + gx];
        l0 = fmaf(v, fw4[(0 * 3 + ci) * 9 + dy * 3 + dx], l0);
        l1 = fmaf(v, fw4[(1 * 3 + ci) * 9 + dy * 3 + dx], l1);
      }
    }
  }
  const float m = fmaxf(l0, l1);
  const float e0 = __expf(l0 - m), e1 = __expf(l1 - m);
  const float inv = 1.f / (e0 + e1);
  score[((size_t)b * 2 + 0) * 4096 + pp] = e0 * inv;
  score[((size_t)b * 2 + 1) * 4096 + pp] = e1 * inv;
}

// ---------------- blend: out = s0*f + s1*aligned (packed C8 sources) ----------------
__global__ __launch_bounds__(256) void blend2_k(
    const float* __restrict__ score, const u32* __restrict__ fpk,
    const u32* __restrict__ algpk, float* __restrict__ out)
{
  const int t = blockIdx.x * 256 + threadIdx.x;   // (b, cgrp, px)
  const int px = t & 4095;
  const int cg = (t >> 12) & 31;
  const int b = t >> 17;
  const u32 abase = (u32)b * 1048576u + (u32)cg * 32768u + (u32)px * 8u;
  const u4v f0 = *reinterpret_cast<const u4v*>(fpk + abase);
  const u4v f1 = *reinterpret_cast<const u4v*>(fpk + abase + 4);
  const u4v a0 = *reinterpret_cast<const u4v*>(algpk + abase);
  const u4v a1 = *reinterpret_cast<const u4v*>(algpk + abase + 4);
  const float s0 = score[((size_t)b * 2 + 0) * 4096 + px];
  const float s1 = score[((size_t)b * 2 + 1) * 4096 + px];
  const size_t ob = (((size_t)b * 256 + cg * 8) << 12) + px;
#pragma unroll
  for (int j = 0; j < 8; ++j) {
    const u32 uf = (j < 4) ? f0[j] : f1[j - 4];
    const u32 ua = (j < 4) ? a0[j] : a1[j - 4];
    out[ob + ((size_t)j << 12)] = s0 * unpackf(uf) + s1 * unpackf(ua);
  }
}

extern "C" void kernel_launch(void* const* d_in, const int* in_sizes, int n_in,
                              void* d_out, int out_size, void* d_ws, size_t ws_size,
                              hipStream_t stream) {
  const float* f   = (const float*)d_in[0];
  const float* fh  = (const float*)d_in[1];
  const float* aw1 = (const float*)d_in[2];
  const float* ab1 = (const float*)d_in[3];
  const float* aw2 = (const float*)d_in[4];
  const float* ab2 = (const float*)d_in[5];
  const float* aw3 = (const float*)d_in[6];
  const float* ab3 = (const float*)d_in[7];
  const float* fw1 = (const float*)d_in[8];
  const float* fb1 = (const float*)d_in[9];
  const float* fw2 = (const float*)d_in[10];
  const float* fb2 = (const float*)d_in[11];
  const float* fw3 = (const float*)d_in[12];
  const float* fb3 = (const float*)d_in[13];
  const float* fw4 = (const float*)d_in[14];
  const float* fb4 = (const float*)d_in[15];
  float* out = (float*)d_out;

  // ---------- workspace layout (total 170,524,672 B) ----------
  char* p = (char*)d_ws;
  float* att    = (float*)p;  p += (size_t)2654208 * 4;
  float* g2     = (float*)p;  p += (size_t)524288 * 4;
  float* g3b    = (float*)p;  p += (size_t)98304 * 4;
  float* scoreb = (float*)p;  p += (size_t)65536 * 4;
  u32* fpk      = (u32*)p;    p += (size_t)8388608 * 4;
  u32* fhpk     = (u32*)p;    p += (size_t)8388608 * 4;
  u32* algpk    = (u32*)p;    p += (size_t)8388608 * 4;
  u32* a1pk     = (u32*)p;    p += (size_t)8921088 * 4;   // padded C8, 256 ch
  u32* a2pk     = (u32*)p;    p += (size_t)4460544 * 4;   // padded C8, 128 ch
  __bf16* w1h   = (__bf16*)p; p += (size_t)131072 * 2;
  __bf16* w1l   = (__bf16*)p; p += (size_t)131072 * 2;
  __bf16* w2h   = (__bf16*)p; p += (size_t)294912 * 2;
  __bf16* w2l   = (__bf16*)p; p += (size_t)294912 * 2;
  __bf16* w3h   = (__bf16*)p; p += (size_t)147456 * 2;    // CoutPad=128
  __bf16* w3l   = (__bf16*)p; p += (size_t)147456 * 2;
  __bf16* f1h   = (__bf16*)p; p += (size_t)131072 * 2;
  __bf16* f1l   = (__bf16*)p; p += (size_t)131072 * 2;
  __bf16* f2h   = (__bf16*)p; p += (size_t)36864 * 2;
  __bf16* f2l   = (__bf16*)p; p += (size_t)36864 * 2;

  dim3 blk(256);
  // weight packing
  packw_k<<<dim3(512),  blk, 0, stream>>>(aw1, w1h, w1l, 256, 256, 512, 1);
  packw_k<<<dim3(1152), blk, 0, stream>>>(aw2, w2h, w2l, 128, 128, 256, 9);
  packw_k<<<dim3(576),  blk, 0, stream>>>(aw3, w3h, w3l, 81, 128, 128, 9);
  packw_k<<<dim3(512),  blk, 0, stream>>>(fw1, f1h, f1l, 256, 256, 512, 1);
  packw_k<<<dim3(144),  blk, 0, stream>>>(fw2, f2h, f2l, 16, 16, 256, 9);
  // zero padded buffers (borders must be 0; interior rewritten every call)
  hipMemsetAsync(a1pk, 0, (size_t)(8921088 + 4460544) * 4, stream);
  // pack inputs
  packin2_k<<<dim3(4096, 2), blk, 0, stream>>>(f, fh, fpk, fhpk);

  // atten path
  convp_k<512, 2, 4, 1, 1, 256, true,  true ><<<dim3(512, 2), blk, 0, stream>>>(fpk, fhpk, w1h, w1l, ab1, nullptr, a1pk, 256);
  convp_k<256, 2, 4, 9, 1, 128, true,  false><<<dim3(512, 1), blk, 0, stream>>>(a1pk, nullptr, w2h, w2l, ab2, nullptr, a2pk, 128);
  convp_k<128, 2, 4, 9, 0,  81, false, false><<<dim3(512, 1), blk, 0, stream>>>(a2pk, nullptr, w3h, w3l, ab3, att, nullptr, 81);
  // assemble
  assemble3_k<<<dim3(64, 8), blk, 0, stream>>>(att, fh, algpk);
  // final path
  convp_k<512, 2, 4, 1, 1, 256, true,  true ><<<dim3(512, 2), blk, 0, stream>>>(fpk, algpk, f1h, f1l, fb1, nullptr, a1pk, 256);
  convp_k<256, 1, 1, 9, 0,  16, true,  false><<<dim3(128, 1), blk, 0, stream>>>(a1pk, nullptr, f2h, f2l, fb2, g2, nullptr, 16);
  conv3x3_k<3, false><<<dim3(16, 1, 8), blk, 0, stream>>>(g2, fw3, fb3, g3b, 16, 3);
  logits_softmax_k<<<dim3(128), blk, 0, stream>>>(g3b, fw4, fb4, scoreb);
  blend2_k<<<dim3(4096), blk, 0, stream>>>(scoreb, fpk, algpk, out);
}

// Round 6
// 425.372 us; speedup vs baseline: 2.6018x; 1.2116x over previous
//
#include <hip/hip_runtime.h>

typedef __bf16 bf8 __attribute__((ext_vector_type(8)));
typedef float f4 __attribute__((ext_vector_type(4)));
typedef unsigned int u32;
typedef u32 u4v __attribute__((ext_vector_type(4)));

__device__ __forceinline__ u32 packf(float v) {
  const __bf16 h = (__bf16)v;
  const __bf16 l = (__bf16)(v - (float)h);
  return ((u32)__builtin_bit_cast(unsigned short, h) << 16) |
         (u32)__builtin_bit_cast(unsigned short, l);
}
__device__ __forceinline__ float unpackf(u32 u) {
  const float hi = __builtin_bit_cast(float, u & 0xffff0000u);
  const float lo = __builtin_bit_cast(float, u << 16);
  return hi + lo;
}

// ---------------- weight pack: fp32 [Cout][Cin][taps] -> bf16 hi/lo [CoutPad][taps][Cin] ----------------
__global__ __launch_bounds__(256) void packw_k(
    const float* __restrict__ w, __bf16* __restrict__ whi, __bf16* __restrict__ wlo,
    int Cout, int CoutPad, int Cin, int taps)
{
  const int idx = blockIdx.x * 256 + threadIdx.x;
  const int tot = CoutPad * taps * Cin;
  if (idx >= tot) return;
  const int co = idx / (taps * Cin);
  const int rem = idx - co * taps * Cin;
  const int tap = rem / Cin;
  const int ci = rem - tap * Cin;
  const float v = (co < Cout) ? w[((size_t)co * Cin + ci) * taps + tap] : 0.f;
  const __bf16 h = (__bf16)v;
  whi[idx] = h;
  wlo[idx] = (__bf16)(v - (float)h);
}

// ---------------- zero ONLY the halo borders of the padded C8 conv buffers ----------------
// planes: 256 (a1: 8b*32cg) then 128 (a2: 8b*16cg). 260 border px/plane, 8 u32 each.
__global__ __launch_bounds__(256) void zerobord_k(
    u32* __restrict__ a1pk, u32* __restrict__ a2pk)
{
  const int t = blockIdx.x * 256 + threadIdx.x;
  const int tot = (256 + 128) * 260;
  if (t >= tot) return;
  const int plane = t / 260;
  const int e = t - plane * 260;
  int r, c;
  if (e < 66)       { r = 0;        c = e; }
  else if (e < 132) { r = 65;       c = e - 66; }
  else if (e < 196) { r = e - 131;  c = 0; }
  else              { r = e - 195;  c = 65; }
  u32* dst = (plane < 256) ? a1pk + (size_t)plane * 34848u
                           : a2pk + (size_t)(plane - 256) * 34848u;
  const u32 a = (u32)(r * 66 + c) * 8u;
  u4v z{0u, 0u, 0u, 0u};
  *reinterpret_cast<u4v*>(dst + a) = z;
  *reinterpret_cast<u4v*>(dst + a + 4) = z;
}

// ---------------- pack f/fh fp32 NCHW -> C8 packed u32 [b][C/8][4096][8] ----------------
__global__ __launch_bounds__(256) void packin2_k(
    const float* __restrict__ f, const float* __restrict__ fh,
    u32* __restrict__ fpk, u32* __restrict__ fhpk)
{
  const int t = blockIdx.x * 256 + threadIdx.x;   // (b, cgrp, px)
  const int px = t & 4095;
  const int cg = (t >> 12) & 31;
  const int b = t >> 17;
  const float* __restrict__ src = blockIdx.y ? fh : f;
  u32* __restrict__ dst = blockIdx.y ? fhpk : fpk;
  const size_t ib = (((size_t)b * 256 + cg * 8) << 12) + px;
  u4v o0, o1;
#pragma unroll
  for (int j = 0; j < 8; ++j) {
    const u32 p = packf(src[ib + ((size_t)j << 12)]);
    if (j < 4) o0[j] = p; else o1[j - 4] = p;
  }
  const u32 oadr = (u32)b * 1048576u + (u32)cg * 32768u + (u32)px * 8u;
  *reinterpret_cast<u4v*>(dst + oadr) = o0;
  *reinterpret_cast<u4v*>(dst + oadr + 4) = o1;
}

// ---------------- MFMA implicit-GEMM conv, C8-packed inputs ----------------
template<int CIN, int COT, int WCO, int TAPS, int OUTM, int COUTB, bool RELU, bool CONCAT>
__global__ __launch_bounds__(256, 2) void convp_k(
    const u32* __restrict__ inA, const u32* __restrict__ inB,
    const __bf16* __restrict__ whi, const __bf16* __restrict__ wlo,
    const float* __restrict__ bias,
    float* __restrict__ outF, u32* __restrict__ outP, int Cout)
{
  constexpr int RPB = 4 / WCO;
  constexpr int KQ = CIN / 32;
  constexpr int NS = TAPS * KQ;                       // all even
  constexpr u32 PL8IN = (TAPS == 9) ? 34848u : 32768u;
  constexpr u32 BSTR = CONCAT ? 1048576u : (u32)(CIN / 8) * PL8IN;
  constexpr u32 OBSTR = (u32)(COUTB / 8) * 34848u;

  const int lane = threadIdx.x & 63;
  const int wv = threadIdx.x >> 6;
  const int wco = (WCO == 4) ? wv : 0;
  const int rg = (WCO == 4) ? 0 : wv;
  const int pb = blockIdx.x * RPB + rg;
  const int b = pb >> 6, y = pb & 63;
  const int co0 = blockIdx.y * (16 * COT * WCO) + wco * (16 * COT);
  if (co0 >= Cout) return;                            // wave-uniform; no barriers in kernel
  const int colb = lane & 15, g = lane >> 4;

  f4 acc[COT][4];
#pragma unroll
  for (int t = 0; t < COT; ++t)
#pragma unroll
    for (int fr = 0; fr < 4; ++fr) acc[t][fr] = f4{0.f, 0.f, 0.f, 0.f};

  auto LOAD = [&](int s, u4v (&B)[4][2], bf8 (&AH)[COT], bf8 (&AL)[COT]) {
    int tap, kq;
    if (TAPS == 9) { kq = (s * 57) >> 9; tap = s - kq * 9; }   // s = kq*9+tap
    else { kq = s; tap = 0; }
    const int cib = (kq << 5) + g * 8;
    int rc;
    if (TAPS == 9) {
      const int dy = (tap * 11) >> 5;                 // tap/3
      const int dxm1 = tap - dy * 3 - 1;
      const int gy = y + dy - 1;                      // -1..64, padded
      rc = (gy + 1) * 66 + colb + dxm1 + 1;
    } else {
      rc = (y << 6) + colb;
    }
    const u32* src = inA;
    int cg = cib >> 3;
    if (CONCAT) { if (cib >= 256) src = inB; cg = (cib & 255) >> 3; }
    const u32 off = (u32)b * BSTR + (u32)cg * PL8IN + (u32)rc * 8u;
#pragma unroll
    for (int fr = 0; fr < 4; ++fr) {
      B[fr][0] = *reinterpret_cast<const u4v*>(src + off + fr * 128u);
      B[fr][1] = *reinterpret_cast<const u4v*>(src + off + fr * 128u + 4u);
    }
#pragma unroll
    for (int t = 0; t < COT; ++t) {
      const size_t wo = (size_t)(co0 + t * 16 + colb) * (TAPS * CIN) + tap * CIN + cib;
      AH[t] = *reinterpret_cast<const bf8*>(whi + wo);
      AL[t] = *reinterpret_cast<const bf8*>(wlo + wo);
    }
  };

  auto COMPUTE = [&](u4v (&B)[4][2], bf8 (&AH)[COT], bf8 (&AL)[COT]) {
#pragma unroll
    for (int fr = 0; fr < 4; ++fr) {
      u4v hw, lw;
#pragma unroll
      for (int d = 0; d < 4; ++d) {
        const u32 E = (d < 2) ? B[fr][0][2 * d]     : B[fr][1][2 * d - 4];
        const u32 O = (d < 2) ? B[fr][0][2 * d + 1] : B[fr][1][2 * d - 3];
        hw[d] = (E >> 16) | (O & 0xffff0000u);        // foldable to v_perm_b32
        lw[d] = (E & 0xffffu) | (O << 16);
      }
      const bf8 bh = __builtin_bit_cast(bf8, hw);
      const bf8 bl = __builtin_bit_cast(bf8, lw);
#pragma unroll
      for (int t = 0; t < COT; ++t) {
        acc[t][fr] = __builtin_amdgcn_mfma_f32_16x16x32_bf16(AH[t], bh, acc[t][fr], 0, 0, 0);
        acc[t][fr] = __builtin_amdgcn_mfma_f32_16x16x32_bf16(AH[t], bl, acc[t][fr], 0, 0, 0);
        acc[t][fr] = __builtin_amdgcn_mfma_f32_16x16x32_bf16(AL[t], bh, acc[t][fr], 0, 0, 0);
      }
    }
  };

  u4v B0[4][2], B1[4][2];
  bf8 AH0[COT], AL0[COT], AH1[COT], AL1[COT];
  LOAD(0, B0, AH0, AL0);
  for (int s = 0; s < NS; s += 2) {
    LOAD(s + 1, B1, AH1, AL1);        // NS even -> s+1 always valid
    COMPUTE(B0, AH0, AL0);
    if (s + 2 < NS) LOAD(s + 2, B0, AH0, AL0);
    COMPUTE(B1, AH1, AL1);
  }

  if (OUTM == 0) {
    const size_t ob = ((size_t)b * COUTB) << 12;
#pragma unroll
    for (int t = 0; t < COT; ++t)
#pragma unroll
      for (int r = 0; r < 4; ++r) {
        const int co = co0 + t * 16 + g * 4 + r;
        if (co < Cout) {
          const float bv = bias[co];
#pragma unroll
          for (int fr = 0; fr < 4; ++fr) {
            float v = acc[t][fr][r] + bv;
            if (RELU) v = fmaxf(v, 0.f);
            outF[ob + ((size_t)co << 12) + (y << 6) + fr * 16 + colb] = v;
          }
        }
      }
  } else {
#pragma unroll
    for (int t = 0; t < COT; ++t) {
      const int cbase = co0 + t * 16 + g * 4;
      float bv[4];
#pragma unroll
      for (int r = 0; r < 4; ++r) bv[r] = bias[cbase + r];
#pragma unroll
      for (int fr = 0; fr < 4; ++fr) {
        u4v pk;
#pragma unroll
        for (int r = 0; r < 4; ++r) {
          float v = acc[t][fr][r] + bv[r];
          if (RELU) v = fmaxf(v, 0.f);
          pk[r] = packf(v);
        }
        const int px = fr * 16 + colb;
        const u32 oadr = (u32)b * OBSTR + (u32)(cbase >> 3) * 34848u
                       + (u32)((y + 1) * 66 + px + 1) * 8u + (u32)(cbase & 7);
        *reinterpret_cast<u4v*>(outP + oadr) = pk;
      }
    }
  }
}

// ---------------- assemble v4: fp32 compute, channel-split across blocks ----------------
// grid (64 y, 8 b, 4 cg). Each thread: 4 channels x 4 x-positions. acc[4][4].
__global__ __launch_bounds__(256, 4) void assemble4_k(
    const float* __restrict__ atten, const float* __restrict__ fh,
    u32* __restrict__ algpk)
{
  __shared__ float att[81][64];
  const int y = blockIdx.x, b = blockIdx.y, cg = blockIdx.z;
  for (int e = threadIdx.x; e < 81 * 64; e += 256) {
    const int i = e >> 6, x = e & 63;
    att[i][x] = atten[(((size_t)b * 81 + i) << 12) + (y << 6) + x];
  }
  __syncthreads();

  const int quad = threadIdx.x & 15, x0 = quad << 2;
  const int csub = threadIdx.x >> 4;

  float acc[4][4];
#pragma unroll
  for (int i = 0; i < 4; ++i) {
    acc[i][0] = 0.f; acc[i][1] = 0.f; acc[i][2] = 0.f; acc[i][3] = 0.f;
  }

#pragma unroll
  for (int dy = 0; dy < 9; ++dy) {
    const int gy = y + dy - 4;
    if (gy < 0 || gy >= 64) continue;   // block-uniform
    float av[9][4];
#pragma unroll
    for (int dx = 0; dx < 9; ++dx) {
      const float4 q = *reinterpret_cast<const float4*>(&att[dy * 9 + dx][x0]);
      av[dx][0] = q.x; av[dx][1] = q.y; av[dx][2] = q.z; av[dx][3] = q.w;
    }
#pragma unroll
    for (int cb = 0; cb < 4; ++cb) {
      const int ch = cg * 64 + cb * 16 + csub;
      const float* row = fh + (((size_t)b * 256 + ch) << 12) + (gy << 6);
      float rv[12];
#pragma unroll
      for (int k = 0; k < 3; ++k) {
        const int col0 = x0 - 4 + (k << 2);
        if (col0 >= 0 && col0 + 3 < 64) {
          const float4 q = *reinterpret_cast<const float4*>(row + col0);
          rv[4 * k + 0] = q.x; rv[4 * k + 1] = q.y; rv[4 * k + 2] = q.z; rv[4 * k + 3] = q.w;
        } else {
#pragma unroll
          for (int jj = 0; jj < 4; ++jj) {
            const int cl = col0 + jj;
            rv[4 * k + jj] = (cl >= 0 && cl < 64) ? row[cl] : 0.f;
          }
        }
      }
#pragma unroll
      for (int dx = 0; dx < 9; ++dx)
#pragma unroll
        for (int j = 0; j < 4; ++j)
          acc[cb][j] = fmaf(av[dx][j], rv[dx + j], acc[cb][j]);
    }
  }

  const u32 pb2 = (u32)b * 1048576u;
#pragma unroll
  for (int cb = 0; cb < 4; ++cb) {
    const int c = cg * 64 + cb * 16 + csub;
    const u32 base = pb2 + (u32)(c >> 3) * 32768u + (u32)(c & 7);
#pragma unroll
    for (int j = 0; j < 4; ++j)
      algpk[base + (u32)((y << 6) + x0 + j) * 8u] = packf(acc[cb][j]);
  }
}

// ---------------- fp32 3x3 conv tail (16->3) ----------------
template<int TCO, bool RELU>
__global__ __launch_bounds__(256) void conv3x3_k(
    const float* __restrict__ in, const float* __restrict__ w,
    const float* __restrict__ bias, float* __restrict__ out,
    int Cin, int Cout)
{
  __shared__ float tile[8][6][66];
  const int b = blockIdx.z;
  const int y0 = blockIdx.x * 4;
  const int co0 = blockIdx.y * TCO;
  const int r = threadIdx.x >> 6;
  const int c = threadIdx.x & 63;

  float acc[TCO];
#pragma unroll
  for (int i = 0; i < TCO; ++i) acc[i] = 0.f;

  for (int ci0 = 0; ci0 < Cin; ci0 += 8) {
    __syncthreads();
    for (int e = threadIdx.x; e < 8 * 6 * 66; e += 256) {
      const int cc = e / 396;
      const int rem = e - cc * 396;
      const int rr = rem / 66;
      const int xx = rem - rr * 66;
      const int gy = y0 + rr - 1;
      const int gx = xx - 1;
      float v = 0.f;
      if (gy >= 0 && gy < 64 && gx >= 0 && gx < 64)
        v = in[(((size_t)b * Cin + ci0 + cc) << 12) + (gy << 6) + gx];
      tile[cc][rr][xx] = v;
    }
    __syncthreads();
    for (int cc = 0; cc < 8; ++cc) {
      const float x00 = tile[cc][r + 0][c + 0], x01 = tile[cc][r + 0][c + 1], x02 = tile[cc][r + 0][c + 2];
      const float x10 = tile[cc][r + 1][c + 0], x11 = tile[cc][r + 1][c + 1], x12 = tile[cc][r + 1][c + 2];
      const float x20 = tile[cc][r + 2][c + 0], x21 = tile[cc][r + 2][c + 1], x22 = tile[cc][r + 2][c + 2];
#pragma unroll
      for (int co = 0; co < TCO; ++co) {
        const float* wp = w + ((size_t)(co0 + co) * Cin + (ci0 + cc)) * 9;
        float s = acc[co];
        s = fmaf(x00, wp[0], s); s = fmaf(x01, wp[1], s); s = fmaf(x02, wp[2], s);
        s = fmaf(x10, wp[3], s); s = fmaf(x11, wp[4], s); s = fmaf(x12, wp[5], s);
        s = fmaf(x20, wp[6], s); s = fmaf(x21, wp[7], s); s = fmaf(x22, wp[8], s);
        acc[co] = s;
      }
    }
  }

#pragma unroll
  for (int co = 0; co < TCO; ++co) {
    if (co0 + co < Cout) {
      float v = acc[co] + bias[co0 + co];
      if (RELU) v = fmaxf(v, 0.f);
      out[(((size_t)b * Cout + (co0 + co)) << 12) + ((y0 + r) << 6) + c] = v;
    }
  }
}

// ---------------- final tiny conv (3->2) + softmax ----------------
__global__ __launch_bounds__(256) void logits_softmax_k(
    const float* __restrict__ g3, const float* __restrict__ fw4,
    const float* __restrict__ fb4, float* __restrict__ score)
{
  const int pix = blockIdx.x * 256 + threadIdx.x;
  const int b = pix >> 12, pp = pix & 4095;
  const int y = pp >> 6, x = pp & 63;
  float l0 = fb4[0], l1 = fb4[1];
#pragma unroll
  for (int ci = 0; ci < 3; ++ci) {
    const float* g = g3 + (((size_t)b * 3 + ci) << 12);
#pragma unroll
    for (int dy = 0; dy < 3; ++dy) {
      const int gy = y + dy - 1;
      if (gy < 0 || gy >= 64) continue;
#pragma unroll
      for (int dx = 0; dx < 3; ++dx) {
        const int gx = x + dx - 1;
        if (gx < 0 || gx >= 64) continue;
        const float v = g[(gy << 6) + gx];
        l0 = fmaf(v, fw4[(0 * 3 + ci) * 9 + dy * 3 + dx], l0);
        l1 = fmaf(v, fw4[(1 * 3 + ci) * 9 + dy * 3 + dx], l1);
      }
    }
  }
  const float m = fmaxf(l0, l1);
  const float e0 = __expf(l0 - m), e1 = __expf(l1 - m);
  const float inv = 1.f / (e0 + e1);
  score[((size_t)b * 2 + 0) * 4096 + pp] = e0 * inv;
  score[((size_t)b * 2 + 1) * 4096 + pp] = e1 * inv;
}

// ---------------- blend: out = s0*f + s1*aligned (packed C8 sources) ----------------
__global__ __launch_bounds__(256) void blend2_k(
    const float* __restrict__ score, const u32* __restrict__ fpk,
    const u32* __restrict__ algpk, float* __restrict__ out)
{
  const int t = blockIdx.x * 256 + threadIdx.x;   // (b, cgrp, px)
  const int px = t & 4095;
  const int cg = (t >> 12) & 31;
  const int b = t >> 17;
  const u32 abase = (u32)b * 1048576u + (u32)cg * 32768u + (u32)px * 8u;
  const u4v f0 = *reinterpret_cast<const u4v*>(fpk + abase);
  const u4v f1 = *reinterpret_cast<const u4v*>(fpk + abase + 4);
  const u4v a0 = *reinterpret_cast<const u4v*>(algpk + abase);
  const u4v a1 = *reinterpret_cast<const u4v*>(algpk + abase + 4);
  const float s0 = score[((size_t)b * 2 + 0) * 4096 + px];
  const float s1 = score[((size_t)b * 2 + 1) * 4096 + px];
  const size_t ob = (((size_t)b * 256 + cg * 8) << 12) + px;
#pragma unroll
  for (int j = 0; j < 8; ++j) {
    const u32 uf = (j < 4) ? f0[j] : f1[j - 4];
    const u32 ua = (j < 4) ? a0[j] : a1[j - 4];
    out[ob + ((size_t)j << 12)] = s0 * unpackf(uf) + s1 * unpackf(ua);
  }
}

extern "C" void kernel_launch(void* const* d_in, const int* in_sizes, int n_in,
                              void* d_out, int out_size, void* d_ws, size_t ws_size,
                              hipStream_t stream) {
  const float* f   = (const float*)d_in[0];
  const float* fh  = (const float*)d_in[1];
  const float* aw1 = (const float*)d_in[2];
  const float* ab1 = (const float*)d_in[3];
  const float* aw2 = (const float*)d_in[4];
  const float* ab2 = (const float*)d_in[5];
  const float* aw3 = (const float*)d_in[6];
  const float* ab3 = (const float*)d_in[7];
  const float* fw1 = (const float*)d_in[8];
  const float* fb1 = (const float*)d_in[9];
  const float* fw2 = (const float*)d_in[10];
  const float* fb2 = (const float*)d_in[11];
  const float* fw3 = (const float*)d_in[12];
  const float* fb3 = (const float*)d_in[13];
  const float* fw4 = (const float*)d_in[14];
  const float* fb4 = (const float*)d_in[15];
  float* out = (float*)d_out;

  // ---------- workspace layout (total ~170.5 MB) ----------
  char* p = (char*)d_ws;
  float* att    = (float*)p;  p += (size_t)2654208 * 4;
  float* g2     = (float*)p;  p += (size_t)524288 * 4;
  float* g3b    = (float*)p;  p += (size_t)98304 * 4;
  float* scoreb = (float*)p;  p += (size_t)65536 * 4;
  u32* fpk      = (u32*)p;    p += (size_t)8388608 * 4;
  u32* fhpk     = (u32*)p;    p += (size_t)8388608 * 4;
  u32* algpk    = (u32*)p;    p += (size_t)8388608 * 4;
  u32* a1pk     = (u32*)p;    p += (size_t)8921088 * 4;   // padded C8, 256 ch
  u32* a2pk     = (u32*)p;    p += (size_t)4460544 * 4;   // padded C8, 128 ch
  __bf16* w1h   = (__bf16*)p; p += (size_t)131072 * 2;
  __bf16* w1l   = (__bf16*)p; p += (size_t)131072 * 2;
  __bf16* w2h   = (__bf16*)p; p += (size_t)294912 * 2;
  __bf16* w2l   = (__bf16*)p; p += (size_t)294912 * 2;
  __bf16* w3h   = (__bf16*)p; p += (size_t)147456 * 2;    // CoutPad=128
  __bf16* w3l   = (__bf16*)p; p += (size_t)147456 * 2;
  __bf16* f1h   = (__bf16*)p; p += (size_t)131072 * 2;
  __bf16* f1l   = (__bf16*)p; p += (size_t)131072 * 2;
  __bf16* f2h   = (__bf16*)p; p += (size_t)36864 * 2;
  __bf16* f2l   = (__bf16*)p; p += (size_t)36864 * 2;

  dim3 blk(256);
  // weight packing
  packw_k<<<dim3(512),  blk, 0, stream>>>(aw1, w1h, w1l, 256, 256, 512, 1);
  packw_k<<<dim3(1152), blk, 0, stream>>>(aw2, w2h, w2l, 128, 128, 256, 9);
  packw_k<<<dim3(576),  blk, 0, stream>>>(aw3, w3h, w3l, 81, 128, 128, 9);
  packw_k<<<dim3(512),  blk, 0, stream>>>(fw1, f1h, f1l, 256, 256, 512, 1);
  packw_k<<<dim3(144),  blk, 0, stream>>>(fw2, f2h, f2l, 16, 16, 256, 9);
  // zero only the halo borders (interior rewritten every call)
  zerobord_k<<<dim3(391), blk, 0, stream>>>(a1pk, a2pk);
  // pack inputs
  packin2_k<<<dim3(4096, 2), blk, 0, stream>>>(f, fh, fpk, fhpk);

  // atten path
  convp_k<512, 2, 4, 1, 1, 256, true,  true ><<<dim3(512, 2), blk, 0, stream>>>(fpk, fhpk, w1h, w1l, ab1, nullptr, a1pk, 256);
  convp_k<256, 2, 4, 9, 1, 128, true,  false><<<dim3(512, 1), blk, 0, stream>>>(a1pk, nullptr, w2h, w2l, ab2, nullptr, a2pk, 128);
  convp_k<128, 2, 4, 9, 0,  81, false, false><<<dim3(512, 1), blk, 0, stream>>>(a2pk, nullptr, w3h, w3l, ab3, att, nullptr, 81);
  // assemble
  assemble4_k<<<dim3(64, 8, 4), blk, 0, stream>>>(att, fh, algpk);
  // final path
  convp_k<512, 2, 4, 1, 1, 256, true,  true ><<<dim3(512, 2), blk, 0, stream>>>(fpk, algpk, f1h, f1l, fb1, nullptr, a1pk, 256);
  convp_k<256, 1, 1, 9, 0,  16, true,  false><<<dim3(128, 1), blk, 0, stream>>>(a1pk, nullptr, f2h, f2l, fb2, g2, nullptr, 16);
  conv3x3_k<3, false><<<dim3(16, 1, 8), blk, 0, stream>>>(g2, fw3, fb3, g3b, 16, 3);
  logits_softmax_k<<<dim3(128), blk, 0, stream>>>(g3b, fw4, fb4, scoreb);
  blend2_k<<<dim3(4096), blk, 0, stream>>>(scoreb, fpk, algpk, out);
}